// Round 2
// baseline (336.502 us; speedup 1.0000x reference)
//
#include <hip/hip_runtime.h>
#include <hip/hip_bf16.h>
#include <cstdint>
#include <cstddef>

typedef float f32x4 __attribute__((ext_vector_type(4)));
typedef short s16x8 __attribute__((ext_vector_type(8)));

// ---------------- workspace layout (bytes) ----------------
#define OFF_IDX   0ull
#define OFF_XB    4096ull        // [2560][1024] bf16 (X rows 0..2047, rel_emb rows 2048..2559)
#define OFF_WT    5246976ull     // 4 x [1024 n][1024 k] bf16 (Wq,Wk,Wv,Wo transposed)
#define OFF_Q     13635584ull    // [32 bh][1024][64] bf16
#define OFF_K     17829888ull    // [32 bh][1024][64] bf16
#define OFF_VT    22024192ull    // [32 bh][64 d][1024 l] bf16
#define OFF_POSQ  26218496ull    // [16 h][512][64] bf16
#define OFF_POSK  27267072ull    // [16 h][512][64] bf16
#define OFF_C2P   28315648ull    // [32 bh][1024][512] bf16
#define OFF_P2C   61870080ull    // [32 bh][1024][512] bf16
#define OFF_CTX   95424512ull    // [2048][1024] bf16
#define OFF_X     99618816ull    // [2048][1024] fp32 (pre-LN)
// total: 108,007,424 bytes

#define INV_SCALE 0.07216878364870322f  // 1/sqrt(64*3)

__device__ __forceinline__ short f2bf(float f) {
  unsigned u = __builtin_bit_cast(unsigned, f);
  unsigned r = (u + 0x7fffu + ((u >> 16) & 1u)) >> 16;
  return (short)r;
}
__device__ __forceinline__ float bf2f(short h) {
  unsigned u = ((unsigned)(unsigned short)h) << 16;
  return __builtin_bit_cast(float, u);
}

// ---------------- K0: log-bucket index table ----------------
// idx[d+1023] = clip(bucket(d)+256, 0, 511), d = q-k in [-1023,1023]
__global__ void build_idx(char* wsb) {
  int i = blockIdx.x * 256 + threadIdx.x;
  if (i >= 2047) return;
  int d = i - 1023;
  int ad = d < 0 ? -d : d;
  int bucket;
  if (ad <= 128) {
    bucket = d;
  } else {
    // denominator matches reference: np.float32(np.log(511/128)) computed in f64
    const float denom = 1.38433933f;
    float lp = ceilf(logf((float)ad * (1.0f / 128.0f)) / denom * 127.0f) + 128.0f;
    bucket = (int)lp * (d > 0 ? 1 : -1);
  }
  int idx = bucket + 256;
  idx = idx < 0 ? 0 : (idx > 511 ? 511 : idx);
  ((short*)(wsb + OFF_IDX))[i] = (short)idx;
}

// ---------------- K1: convert [hidden; rel_emb] -> bf16 ----------------
__global__ __launch_bounds__(256) void convert_x(const float* __restrict__ hidden,
                                                 const float* __restrict__ rel,
                                                 char* __restrict__ wsb) {
  size_t gid = (size_t)blockIdx.x * 256 + threadIdx.x;  // 655360 float4 groups
  const float* src = (gid < 524288) ? (hidden + gid * 4) : (rel + (gid - 524288) * 4);
  float4 v = *(const float4*)src;
  short* dst = (short*)(wsb + OFF_XB) + gid * 4;
  short4 o;
  o.x = f2bf(v.x); o.y = f2bf(v.y); o.z = f2bf(v.z); o.w = f2bf(v.w);
  *(short4*)dst = o;
}

// ---------------- K2: transpose+convert weights -> Wt[n][k] bf16 ----------------
__global__ __launch_bounds__(256) void transpose_w(const float* __restrict__ Wq,
                                                   const float* __restrict__ Wk,
                                                   const float* __restrict__ Wv,
                                                   const float* __restrict__ Wo,
                                                   char* __restrict__ wsb) {
  int z = blockIdx.z;
  const float* W = (z == 0) ? Wq : (z == 1) ? Wk : (z == 2) ? Wv : Wo;
  short* out = (short*)(wsb + OFF_WT) + (size_t)z * 1048576;
  int n0 = blockIdx.x * 32, k0 = blockIdx.y * 32;
  int tx = threadIdx.x & 31, ty = threadIdx.x >> 5;  // 32 x 8
  __shared__ float t[32][33];
#pragma unroll
  for (int i = 0; i < 4; ++i)
    t[ty + 8 * i][tx] = W[(size_t)(k0 + ty + 8 * i) * 1024 + n0 + tx];
  __syncthreads();
#pragma unroll
  for (int i = 0; i < 4; ++i)
    out[(size_t)(n0 + ty + 8 * i) * 1024 + k0 + tx] = f2bf(t[tx][ty + 8 * i]);
}

// ---------------- GEMM (m97-style 128x128x32, 4 waves) ----------------
// mode 0: z in {0,1,2}: [Xb;rel] @ Wt[z] + b -> q/posq, k/posk, Vt   (M=2560/2048)
// mode 1: z = which*32+bh: q|k [1024,64] @ posk|posq[h] [512,64]^T -> c2p|p2c att
// mode 2: ctx @ Wt[3] + bo + hidden -> X fp32 (pre-LN)
__global__ __launch_bounds__(256) void gemm_all(char* __restrict__ wsb, int mode,
    const float* __restrict__ bq, const float* __restrict__ bk, const float* __restrict__ bv,
    const float* __restrict__ bo, const float* __restrict__ hidden) {
  const int tid = threadIdx.x;
  const int w = tid >> 6, l = tid & 63;
  const int lr = l & 15, lg = l >> 4;
  const int wr = (w >> 1) * 64, wc = (w & 1) * 64;
  const int n0 = blockIdx.x * 128, m0 = blockIdx.y * 128;
  const int z = blockIdx.z;

  const short* A;
  const short* B;
  int lda, ldb, K;
  if (mode == 0) {
    if (z == 2 && m0 >= 2048) return;
    A = (const short*)(wsb + OFF_XB); lda = 1024;
    B = (const short*)(wsb + OFF_WT) + (size_t)z * 1048576; ldb = 1024;
    K = 1024;
  } else if (mode == 1) {
    int which = z >> 5, bh = z & 31, h = bh & 15;
    A = (const short*)(wsb + (which ? OFF_K : OFF_Q)) + (size_t)bh * 65536; lda = 64;
    B = (const short*)(wsb + (which ? OFF_POSQ : OFF_POSK)) + (size_t)h * 32768; ldb = 64;
    K = 64;
  } else {
    A = (const short*)(wsb + OFF_CTX); lda = 1024;
    B = (const short*)(wsb + OFF_WT) + (size_t)3 * 1048576; ldb = 1024;
    K = 1024;
  }

  __shared__ __align__(16) short Al[128 * 32];
  __shared__ __align__(16) short Bl[128 * 32];

  f32x4 acc[4][4] = {};

  for (int k0 = 0; k0 < K; k0 += 32) {
#pragma unroll
    for (int j = 0; j < 2; ++j) {
      int c = w * 2 + j;                       // chunk: 1024B = 64 lanes x 16B
      int row = c * 16 + (l >> 2), col = (l & 3) * 8;
      const short* ga = A + (size_t)(m0 + row) * lda + k0 + col;
      const short* gb = B + (size_t)(n0 + row) * ldb + k0 + col;
      __builtin_amdgcn_global_load_lds((const __attribute__((address_space(1))) void*)ga,
          (__attribute__((address_space(3))) void*)(Al + c * 512), 16, 0, 0);
      __builtin_amdgcn_global_load_lds((const __attribute__((address_space(1))) void*)gb,
          (__attribute__((address_space(3))) void*)(Bl + c * 512), 16, 0, 0);
    }
    __syncthreads();
    s16x8 af[4], bfr[4];
#pragma unroll
    for (int i = 0; i < 4; ++i) af[i] = *(const s16x8*)&Al[(wr + i * 16 + lr) * 32 + lg * 8];
#pragma unroll
    for (int i = 0; i < 4; ++i) bfr[i] = *(const s16x8*)&Bl[(wc + i * 16 + lr) * 32 + lg * 8];
#pragma unroll
    for (int mi = 0; mi < 4; ++mi)
#pragma unroll
      for (int ni = 0; ni < 4; ++ni)
        acc[mi][ni] = __builtin_amdgcn_mfma_f32_16x16x32_bf16(af[mi], bfr[ni], acc[mi][ni], 0, 0, 0);
    __syncthreads();
  }

  if (mode == 0) {
    const float* bias = (z == 0) ? bq : (z == 1) ? bk : bv;
    short* outq = (short*)(wsb + ((z == 0) ? OFF_Q : (z == 1) ? OFF_K : OFF_VT));
    short* outp = (short*)(wsb + ((z == 0) ? OFF_POSQ : OFF_POSK));
#pragma unroll
    for (int mi = 0; mi < 4; ++mi) {
#pragma unroll
      for (int ni = 0; ni < 4; ++ni) {
        int gcol = n0 + wc + ni * 16 + lr;
        int h = gcol >> 6, d = gcol & 63;
        float bia = bias[gcol];
#pragma unroll
        for (int r = 0; r < 4; ++r) {
          int grow = m0 + wr + mi * 16 + lg * 4 + r;
          short v16 = f2bf(acc[mi][ni][r] + bia);
          if (z == 2) {
            int b = grow >> 10, ll = grow & 1023;
            outq[((size_t)((b * 16 + h) * 64 + d)) * 1024 + ll] = v16;   // Vt [bh][d][l]
          } else if (grow < 2048) {
            int b = grow >> 10, ll = grow & 1023;
            outq[((size_t)((b * 16 + h) * 1024 + ll)) * 64 + d] = v16;   // q/k [bh][l][d]
          } else {
            int s = grow - 2048;
            outp[((size_t)(h * 512 + s)) * 64 + d] = v16;                // pos [h][s][d]
          }
        }
      }
    }
  } else if (mode == 1) {
    int which = z >> 5, bh = z & 31;
    short* C = (short*)(wsb + (which ? OFF_P2C : OFF_C2P)) + (size_t)bh * 524288;
#pragma unroll
    for (int mi = 0; mi < 4; ++mi)
#pragma unroll
      for (int ni = 0; ni < 4; ++ni)
#pragma unroll
        for (int r = 0; r < 4; ++r) {
          int grow = m0 + wr + mi * 16 + lg * 4 + r;
          int gcol = n0 + wc + ni * 16 + lr;
          C[(size_t)grow * 512 + gcol] = f2bf(acc[mi][ni][r]);
        }
  } else {
    float* X = (float*)(wsb + OFF_X);
#pragma unroll
    for (int mi = 0; mi < 4; ++mi)
#pragma unroll
      for (int ni = 0; ni < 4; ++ni) {
        int gcol = n0 + wc + ni * 16 + lr;
        float bia = bo[gcol];
#pragma unroll
        for (int r = 0; r < 4; ++r) {
          int grow = m0 + wr + mi * 16 + lg * 4 + r;
          X[(size_t)grow * 1024 + gcol] =
              acc[mi][ni][r] + bia + hidden[(size_t)grow * 1024 + gcol];
        }
      }
  }
}

// ---------------- K5: flash attention with disentangled bias ----------------
// grid (32 bh, 16 qtiles), 256 threads = 4 waves, 64 q-rows per block, k-tiles of 64
__global__ __launch_bounds__(256) void attn_kernel(char* __restrict__ wsb,
                                                   const int* __restrict__ mask) {
  const int bh = blockIdx.x, qt = blockIdx.y;
  const int b = bh >> 4, h = bh & 15;
  const int q0 = qt * 64;
  const int tid = threadIdx.x, w = tid >> 6, l = tid & 63;
  const int lr = l & 15, lg = l >> 4;

  const short* qb  = (const short*)(wsb + OFF_Q)  + (size_t)bh * 65536;
  const short* kb  = (const short*)(wsb + OFF_K)  + (size_t)bh * 65536;
  const short* vtb = (const short*)(wsb + OFF_VT) + (size_t)bh * 65536;
  const short* c2pb = (const short*)(wsb + OFF_C2P) + (size_t)bh * 524288;
  const short* p2cb = (const short*)(wsb + OFF_P2C) + (size_t)bh * 524288;
  const short* idxg = (const short*)(wsb + OFF_IDX);

  __shared__ __align__(16) short Kl[64][88];    // [key][d], padded (bank-conflict break)
  __shared__ __align__(16) short Vl[64][88];    // [d][key], padded
  __shared__ __align__(16) short Pl[4][16][88]; // per-wave P round-trip
  __shared__ __align__(16) short c2ps[64][128]; // c2p window [q-local][wl]
  __shared__ __align__(16) short p2cs[64][128]; // p2c window [k-local][wl]
  __shared__ short idxt[2048];

  for (int i = tid; i < 2047; i += 256) idxt[i] = idxg[i];

  // Q fragments (held in registers all block)
  s16x8 qf0, qf1;
  {
    int g = q0 + w * 16 + lr;
    const short* qp = qb + (size_t)g * 64 + lg * 8;
    qf0 = *(const s16x8*)qp;
    qf1 = *(const s16x8*)(qp + 32);
  }

  f32x4 acc[4] = {};
  float mrun[4] = {-1e30f, -1e30f, -1e30f, -1e30f};
  float lsum[4] = {0.f, 0.f, 0.f, 0.f};
  __syncthreads();  // idxt ready

  for (int kt = 0; kt < 16; ++kt) {
    const int k0 = kt * 64;
    // ---- stage K tile [key][d] and Vt tile [d][key] ----
    {
      int row = tid >> 2, c0 = (tid & 3) * 16;
      const short* ks = kb + (size_t)(k0 + row) * 64 + c0;
      *(s16x8*)&Kl[row][c0]     = *(const s16x8*)ks;
      *(s16x8*)&Kl[row][c0 + 8] = *(const s16x8*)(ks + 8);
      const short* vs = vtb + (size_t)row * 1024 + k0 + c0;
      *(s16x8*)&Vl[row][c0]     = *(const s16x8*)vs;
      *(s16x8*)&Vl[row][c0 + 8] = *(const s16x8*)(vs + 8);
    }
    // ---- stage bias windows (<=127 wide, monotone idx) ----
    const int lo = idxt[(q0 - k0 - 63) + 1023];
    {
      int row = tid >> 2, j0 = (tid & 3) * 32;
      const short* cs = c2pb + (size_t)(q0 + row) * 512;
      const short* ps = p2cb + (size_t)(k0 + row) * 512;
#pragma unroll
      for (int g2 = 0; g2 < 4; ++g2) {
        int j = j0 + g2 * 8;
        int sc = lo + j;
        if (sc + 7 <= 511) {
          *(s16x8*)&c2ps[row][j] = *(const s16x8*)(cs + sc);
          *(s16x8*)&p2cs[row][j] = *(const s16x8*)(ps + sc);
        } else {
          for (int i2 = 0; i2 < 8; ++i2) {
            int scc = sc + i2; scc = scc > 511 ? 511 : scc;
            c2ps[row][j + i2] = cs[scc];
            p2cs[row][j + i2] = ps[scc];
          }
        }
      }
    }
    __syncthreads();

    // ---- S = Q K^T (wave: 16 q-rows x 64 keys) ----
    f32x4 sf[4];
#pragma unroll
    for (int cb = 0; cb < 4; ++cb) {
      s16x8 kf0 = *(const s16x8*)&Kl[cb * 16 + lr][lg * 8];
      s16x8 kf1 = *(const s16x8*)&Kl[cb * 16 + lr][32 + lg * 8];
      f32x4 z4 = {};
      z4 = __builtin_amdgcn_mfma_f32_16x16x32_bf16(qf0, kf0, z4, 0, 0, 0);
      z4 = __builtin_amdgcn_mfma_f32_16x16x32_bf16(qf1, kf1, z4, 0, 0, 0);
      sf[cb] = z4;
    }

    // ---- bias + mask + scale; online softmax ----
    float pv[4][4];
    float tmax[4] = {-1e30f, -1e30f, -1e30f, -1e30f};
#pragma unroll
    for (int cb = 0; cb < 4; ++cb) {
      int colt = cb * 16 + lr;
      int gk = k0 + colt;
#pragma unroll
      for (int r = 0; r < 4; ++r) {
        int rowt = w * 16 + lg * 4 + r;
        int gq = q0 + rowt;
        int wl = idxt[(gq - gk) + 1023] - lo;
        float bias = bf2f(c2ps[rowt][wl]) + bf2f(p2cs[colt][wl]);
        float sv = (sf[cb][r] + bias) * INV_SCALE;
        int mv = mask[((size_t)b * 1024 + gq) * 1024 + gk];
        sv = mv ? sv : -1e30f;
        pv[cb][r] = sv;
        tmax[r] = fmaxf(tmax[r], sv);
      }
    }
#pragma unroll
    for (int off = 1; off < 16; off <<= 1)
#pragma unroll
      for (int r = 0; r < 4; ++r) tmax[r] = fmaxf(tmax[r], __shfl_xor(tmax[r], off));
    float alpha[4];
#pragma unroll
    for (int r = 0; r < 4; ++r) {
      float mn = fmaxf(mrun[r], tmax[r]);
      alpha[r] = __expf(mrun[r] - mn);
      mrun[r] = mn;
    }
    float rsum[4] = {0.f, 0.f, 0.f, 0.f};
#pragma unroll
    for (int cb = 0; cb < 4; ++cb)
#pragma unroll
      for (int r = 0; r < 4; ++r) {
        float p = __expf(pv[cb][r] - mrun[r]);
        pv[cb][r] = p;
        rsum[r] += p;
      }
#pragma unroll
    for (int off = 1; off < 16; off <<= 1)
#pragma unroll
      for (int r = 0; r < 4; ++r) rsum[r] += __shfl_xor(rsum[r], off);
#pragma unroll
    for (int r = 0; r < 4; ++r) lsum[r] = lsum[r] * alpha[r] + rsum[r];
#pragma unroll
    for (int d2 = 0; d2 < 4; ++d2)
#pragma unroll
      for (int r = 0; r < 4; ++r) acc[d2][r] *= alpha[r];

    // ---- P -> LDS (per-wave region; same-wave RAW, in-order LDS pipe) ----
#pragma unroll
    for (int cb = 0; cb < 4; ++cb)
#pragma unroll
      for (int r = 0; r < 4; ++r)
        Pl[w][lg * 4 + r][cb * 16 + lr] = f2bf(pv[cb][r]);

    // ---- acc += P V ----
    s16x8 pa0 = *(const s16x8*)&Pl[w][lr][lg * 8];
    s16x8 pa1 = *(const s16x8*)&Pl[w][lr][32 + lg * 8];
#pragma unroll
    for (int d2 = 0; d2 < 4; ++d2) {
      s16x8 vf0 = *(const s16x8*)&Vl[d2 * 16 + lr][lg * 8];
      s16x8 vf1 = *(const s16x8*)&Vl[d2 * 16 + lr][32 + lg * 8];
      acc[d2] = __builtin_amdgcn_mfma_f32_16x16x32_bf16(pa0, vf0, acc[d2], 0, 0, 0);
      acc[d2] = __builtin_amdgcn_mfma_f32_16x16x32_bf16(pa1, vf1, acc[d2], 0, 0, 0);
    }
    __syncthreads();
  }

  // ---- epilogue: ctx[b][q][h*64+d] bf16 ----
  short* ctx = (short*)(wsb + OFF_CTX);
#pragma unroll
  for (int r = 0; r < 4; ++r) {
    float inv = 1.0f / lsum[r];
    int gq = q0 + w * 16 + lg * 4 + r;
#pragma unroll
    for (int d2 = 0; d2 < 4; ++d2) {
      int gd = h * 64 + d2 * 16 + lr;
      ctx[((size_t)b * 1024 + gq) * 1024 + gd] = f2bf(acc[d2][r] * inv);
    }
  }
}

// ---------------- K7: LayerNorm ----------------
__global__ __launch_bounds__(256) void ln_kernel(const char* __restrict__ wsb,
                                                 const float* __restrict__ gamma,
                                                 const float* __restrict__ beta,
                                                 float* __restrict__ out) {
  int row = blockIdx.x, tid = threadIdx.x;
  const float* x = (const float*)(wsb + OFF_X) + (size_t)row * 1024;
  float4 v = ((const float4*)x)[tid];
  float s = v.x + v.y + v.z + v.w;
  float s2 = v.x * v.x + v.y * v.y + v.z * v.z + v.w * v.w;
#pragma unroll
  for (int off = 1; off < 64; off <<= 1) {
    s += __shfl_xor(s, off);
    s2 += __shfl_xor(s2, off);
  }
  __shared__ float ss[4], ss2[4];
  if ((tid & 63) == 0) { ss[tid >> 6] = s; ss2[tid >> 6] = s2; }
  __syncthreads();
  s = ss[0] + ss[1] + ss[2] + ss[3];
  s2 = ss2[0] + ss2[1] + ss2[2] + ss2[3];
  float mu = s * (1.0f / 1024.0f);
  float var = s2 * (1.0f / 1024.0f) - mu * mu;
  float rstd = rsqrtf(var + 1e-7f);
  float4 g = ((const float4*)gamma)[tid];
  float4 be = ((const float4*)beta)[tid];
  float4 o;
  o.x = (v.x - mu) * rstd * g.x + be.x;
  o.y = (v.y - mu) * rstd * g.y + be.y;
  o.z = (v.z - mu) * rstd * g.z + be.z;
  o.w = (v.w - mu) * rstd * g.w + be.w;
  ((float4*)(out + (size_t)row * 1024))[tid] = o;
}

// ---------------- launch ----------------
extern "C" void kernel_launch(void* const* d_in, const int* in_sizes, int n_in,
                              void* d_out, int out_size, void* d_ws, size_t ws_size,
                              hipStream_t stream) {
  const float* hidden = (const float*)d_in[0];
  const int*   mask   = (const int*)d_in[1];
  const float* rel    = (const float*)d_in[2];
  const float* Wq = (const float*)d_in[3];
  const float* bq = (const float*)d_in[4];
  const float* Wk = (const float*)d_in[5];
  const float* bk = (const float*)d_in[6];
  const float* Wv = (const float*)d_in[7];
  const float* bv = (const float*)d_in[8];
  const float* Wo = (const float*)d_in[9];
  const float* bo = (const float*)d_in[10];
  const float* gamma = (const float*)d_in[11];
  const float* beta  = (const float*)d_in[12];
  char* ws = (char*)d_ws;
  float* out = (float*)d_out;

  build_idx<<<dim3(8), dim3(256), 0, stream>>>(ws);
  convert_x<<<dim3(2560), dim3(256), 0, stream>>>(hidden, rel, ws);
  transpose_w<<<dim3(32, 32, 4), dim3(256), 0, stream>>>(Wq, Wk, Wv, Wo, ws);
  // QKV + pos projections (z=0:Wq, 1:Wk, 2:Wv)
  gemm_all<<<dim3(8, 20, 3), dim3(256), 0, stream>>>(ws, 0, bq, bk, bv, bo, hidden);
  // c2p_att / p2c_att batched over (which, bh)
  gemm_all<<<dim3(4, 8, 64), dim3(256), 0, stream>>>(ws, 1, bq, bk, bv, bo, hidden);
  attn_kernel<<<dim3(32, 16), dim3(256), 0, stream>>>(ws, mask);
  // output projection + bias + residual -> X fp32
  gemm_all<<<dim3(8, 16, 1), dim3(256), 0, stream>>>(ws, 2, bq, bk, bv, bo, hidden);
  ln_kernel<<<dim3(2048), dim3(256), 0, stream>>>(ws, gamma, beta, out);
}

// Round 4
// 298.848 us; speedup vs baseline: 1.1260x; 1.1260x over previous
//
#include <hip/hip_runtime.h>
#include <hip/hip_bf16.h>
#include <cstdint>
#include <cstddef>

typedef float f32x4 __attribute__((ext_vector_type(4)));
typedef short s16x8 __attribute__((ext_vector_type(8)));

// ---------------- workspace layout (bytes) ----------------
#define OFF_IDX   0ull
#define OFF_XB    4096ull        // [2560][1024] bf16 (X rows 0..2047, rel_emb rows 2048..2559)
#define OFF_WT    5246976ull     // 4 x [1024 n][1024 k] bf16 (Wq,Wk,Wv,Wo transposed)
#define OFF_Q     13635584ull    // [32 bh][1024][64] bf16
#define OFF_K     17829888ull    // [32 bh][1024][64] bf16
#define OFF_VT    22024192ull    // [32 bh][64 d][1024 l] bf16
#define OFF_POSQ  26218496ull    // [16 h][512][64] bf16
#define OFF_POSK  27267072ull    // [16 h][512][64] bf16
#define OFF_MB    28315648ull    // [2][16][1024] uint64 mask bitwords (256 KB)
#define OFF_CTX   95424512ull    // [2048][1024] bf16
#define OFF_X     99618816ull    // [2048][1024] fp32 (pre-LN)

#define INV_SCALE 0.07216878364870322f  // 1/sqrt(64*3)

__device__ __forceinline__ short f2bf(float f) {
  unsigned u = __builtin_bit_cast(unsigned, f);
  unsigned r = (u + 0x7fffu + ((u >> 16) & 1u)) >> 16;
  return (short)r;
}
__device__ __forceinline__ float bf2f(short h) {
  unsigned u = ((unsigned)(unsigned short)h) << 16;
  return __builtin_bit_cast(float, u);
}

// ---------------- K0: log-bucket index table ----------------
// idx[d+1023] = clip(bucket(d)+256, 0, 511), d = q-k in [-1023,1023]
__global__ void build_idx(char* wsb) {
  int i = blockIdx.x * 256 + threadIdx.x;
  if (i >= 2047) return;
  int d = i - 1023;
  int ad = d < 0 ? -d : d;
  int bucket;
  if (ad <= 128) {
    bucket = d;
  } else {
    // denominator matches reference: np.float32(np.log(511/128)) computed in f64
    const float denom = 1.38433933f;
    float lp = ceilf(logf((float)ad * (1.0f / 128.0f)) / denom * 127.0f) + 128.0f;
    bucket = (int)lp * (d > 0 ? 1 : -1);
  }
  int idx = bucket + 256;
  idx = idx < 0 ? 0 : (idx > 511 ? 511 : idx);
  ((short*)(wsb + OFF_IDX))[i] = (short)idx;
}

// ---------------- K0b: pack mask into bitwords ----------------
// word[(b*16+kt)*1024+q] bit k = mask[b][q][kt*64+k] != 0
__global__ __launch_bounds__(256) void build_maskbits(const int* __restrict__ mask,
                                                      char* __restrict__ wsb) {
  int word = blockIdx.x * 4 + (threadIdx.x >> 6);   // 32768 words
  int lane = threadIdx.x & 63;
  int q = word & 1023, kt = (word >> 10) & 15, b = word >> 14;
  int mv = mask[((size_t)b * 1024 + q) * 1024 + kt * 64 + lane];
  unsigned long long bits = __ballot(mv != 0);
  if (lane == 0) ((unsigned long long*)(wsb + OFF_MB))[word] = bits;
}

// ---------------- K1: convert [hidden; rel_emb] -> bf16 ----------------
__global__ __launch_bounds__(256) void convert_x(const float* __restrict__ hidden,
                                                 const float* __restrict__ rel,
                                                 char* __restrict__ wsb) {
  size_t gid = (size_t)blockIdx.x * 256 + threadIdx.x;  // 655360 float4 groups
  const float* src = (gid < 524288) ? (hidden + gid * 4) : (rel + (gid - 524288) * 4);
  float4 v = *(const float4*)src;
  short* dst = (short*)(wsb + OFF_XB) + gid * 4;
  short4 o;
  o.x = f2bf(v.x); o.y = f2bf(v.y); o.z = f2bf(v.z); o.w = f2bf(v.w);
  *(short4*)dst = o;
}

// ---------------- K2: transpose+convert weights -> Wt[n][k] bf16 ----------------
__global__ __launch_bounds__(256) void transpose_w(const float* __restrict__ Wq,
                                                   const float* __restrict__ Wk,
                                                   const float* __restrict__ Wv,
                                                   const float* __restrict__ Wo,
                                                   char* __restrict__ wsb) {
  int z = blockIdx.z;
  const float* W = (z == 0) ? Wq : (z == 1) ? Wk : (z == 2) ? Wv : Wo;
  short* out = (short*)(wsb + OFF_WT) + (size_t)z * 1048576;
  int n0 = blockIdx.x * 32, k0 = blockIdx.y * 32;
  int tx = threadIdx.x & 31, ty = threadIdx.x >> 5;  // 32 x 8
  __shared__ float t[32][33];
#pragma unroll
  for (int i = 0; i < 4; ++i)
    t[ty + 8 * i][tx] = W[(size_t)(k0 + ty + 8 * i) * 1024 + n0 + tx];
  __syncthreads();
#pragma unroll
  for (int i = 0; i < 4; ++i)
    out[(size_t)(n0 + ty + 8 * i) * 1024 + k0 + tx] = f2bf(t[tx][ty + 8 * i]);
}

// ---------------- GEMM (m97-style 128x128x32, 4 waves) ----------------
// mode 0: z in {0,1,2}: [Xb;rel] @ Wt[z] + b -> q/posq, k/posk, Vt   (M=2560/2048)
// mode 2: ctx @ Wt[3] + bo + hidden -> X fp32 (pre-LN)
__global__ __launch_bounds__(256) void gemm_all(char* __restrict__ wsb, int mode,
    const float* __restrict__ bq, const float* __restrict__ bk, const float* __restrict__ bv,
    const float* __restrict__ bo, const float* __restrict__ hidden) {
  const int tid = threadIdx.x;
  const int w = tid >> 6, l = tid & 63;
  const int lr = l & 15, lg = l >> 4;
  const int wr = (w >> 1) * 64, wc = (w & 1) * 64;
  const int n0 = blockIdx.x * 128, m0 = blockIdx.y * 128;
  const int z = blockIdx.z;

  const short* A;
  const short* B;
  int lda, ldb, K;
  if (mode == 0) {
    if (z == 2 && m0 >= 2048) return;
    A = (const short*)(wsb + OFF_XB); lda = 1024;
    B = (const short*)(wsb + OFF_WT) + (size_t)z * 1048576; ldb = 1024;
    K = 1024;
  } else {
    A = (const short*)(wsb + OFF_CTX); lda = 1024;
    B = (const short*)(wsb + OFF_WT) + (size_t)3 * 1048576; ldb = 1024;
    K = 1024;
  }

  __shared__ __align__(16) short Al[128 * 32];
  __shared__ __align__(16) short Bl[128 * 32];

  f32x4 acc[4][4] = {};

  for (int k0 = 0; k0 < K; k0 += 32) {
#pragma unroll
    for (int j = 0; j < 2; ++j) {
      int c = w * 2 + j;                       // chunk: 1024B = 64 lanes x 16B
      int row = c * 16 + (l >> 2), col = (l & 3) * 8;
      const short* ga = A + (size_t)(m0 + row) * lda + k0 + col;
      const short* gb = B + (size_t)(n0 + row) * ldb + k0 + col;
      __builtin_amdgcn_global_load_lds((const __attribute__((address_space(1))) void*)ga,
          (__attribute__((address_space(3))) void*)(Al + c * 512), 16, 0, 0);
      __builtin_amdgcn_global_load_lds((const __attribute__((address_space(1))) void*)gb,
          (__attribute__((address_space(3))) void*)(Bl + c * 512), 16, 0, 0);
    }
    __syncthreads();
    s16x8 af[4], bfr[4];
#pragma unroll
    for (int i = 0; i < 4; ++i) af[i] = *(const s16x8*)&Al[(wr + i * 16 + lr) * 32 + lg * 8];
#pragma unroll
    for (int i = 0; i < 4; ++i) bfr[i] = *(const s16x8*)&Bl[(wc + i * 16 + lr) * 32 + lg * 8];
#pragma unroll
    for (int mi = 0; mi < 4; ++mi)
#pragma unroll
      for (int ni = 0; ni < 4; ++ni)
        acc[mi][ni] = __builtin_amdgcn_mfma_f32_16x16x32_bf16(af[mi], bfr[ni], acc[mi][ni], 0, 0, 0);
    __syncthreads();
  }

  if (mode == 0) {
    const float* bias = (z == 0) ? bq : (z == 1) ? bk : bv;
    short* outq = (short*)(wsb + ((z == 0) ? OFF_Q : (z == 1) ? OFF_K : OFF_VT));
    short* outp = (short*)(wsb + ((z == 0) ? OFF_POSQ : OFF_POSK));
#pragma unroll
    for (int mi = 0; mi < 4; ++mi) {
#pragma unroll
      for (int ni = 0; ni < 4; ++ni) {
        int gcol = n0 + wc + ni * 16 + lr;
        int h = gcol >> 6, d = gcol & 63;
        float bia = bias[gcol];
#pragma unroll
        for (int r = 0; r < 4; ++r) {
          int grow = m0 + wr + mi * 16 + lg * 4 + r;
          short v16 = f2bf(acc[mi][ni][r] + bia);
          if (z == 2) {
            int b = grow >> 10, ll = grow & 1023;
            outq[((size_t)((b * 16 + h) * 64 + d)) * 1024 + ll] = v16;   // Vt [bh][d][l]
          } else if (grow < 2048) {
            int b = grow >> 10, ll = grow & 1023;
            outq[((size_t)((b * 16 + h) * 1024 + ll)) * 64 + d] = v16;   // q/k [bh][l][d]
          } else {
            int s = grow - 2048;
            outp[((size_t)(h * 512 + s)) * 64 + d] = v16;                // pos [h][s][d]
          }
        }
      }
    }
  } else {
    float* X = (float*)(wsb + OFF_X);
#pragma unroll
    for (int mi = 0; mi < 4; ++mi)
#pragma unroll
      for (int ni = 0; ni < 4; ++ni) {
        int gcol = n0 + wc + ni * 16 + lr;
        float bia = bo[gcol];
#pragma unroll
        for (int r = 0; r < 4; ++r) {
          int grow = m0 + wr + mi * 16 + lg * 4 + r;
          X[(size_t)grow * 1024 + gcol] =
              acc[mi][ni][r] + bia + hidden[(size_t)grow * 1024 + gcol];
        }
      }
  }
}

// ---------------- K5: fused flash attention with in-place disentangled bias ----------------
// grid (32 bh, 16 qtiles), 256 threads = 4 waves, 64 q-rows/block, k-tiles of 64.
// Per (wave, kt): compute c2p window [16 q][96 i] = Q·posk_win^T and
// p2c window [16 k][96 i] = K·posq_win^T via MFMA (pos arrays are L2-hot),
// gather bias from the windows, online softmax, PV. No c2p/p2c materialization.
__global__ __launch_bounds__(256, 3) void attn_kernel(char* __restrict__ wsb) {
  const int bh = blockIdx.x, qt = blockIdx.y;
  const int b = bh >> 4, h = bh & 15;
  const int q0 = qt * 64;
  const int tid = threadIdx.x, w = tid >> 6, l = tid & 63;
  const int lr = l & 15, lg = l >> 4;

  const short* qb  = (const short*)(wsb + OFF_Q)  + (size_t)bh * 65536;
  const short* kb  = (const short*)(wsb + OFF_K)  + (size_t)bh * 65536;
  const short* vtb = (const short*)(wsb + OFF_VT) + (size_t)bh * 65536;
  const short* pkb = (const short*)(wsb + OFF_POSK) + (size_t)h * 32768;  // [512][64]
  const short* pqb = (const short*)(wsb + OFF_POSQ) + (size_t)h * 32768;
  const short* idxg = (const short*)(wsb + OFF_IDX);
  const unsigned long long* mb =
      (const unsigned long long*)(wsb + OFF_MB) + (size_t)b * 16384;

  // XOR-swizzled [64][64] tiles: 16B chunk c of row r stored at chunk (c ^ (r&7))
  __shared__ __align__(16) short Kl[4096];
  __shared__ __align__(16) short Vl[4096];
  __shared__ __align__(16) short c2pw[4][16][104];  // per-wave c2p window; cols 0..63 reused as P
  __shared__ __align__(16) short p2cw[64][104];     // p2c window, rows = key-local
  __shared__ __align__(16) short iiall[1088];       // idx table slice [q0-1023 .. q0+63]

  for (int j = tid; j < 1087; j += 256) iiall[j] = idxg[q0 + j];

  // Q fragments (held in registers all block)
  s16x8 qf0, qf1;
  {
    int g = q0 + w * 16 + lr;
    const short* qp = qb + (size_t)g * 64 + lg * 8;
    qf0 = *(const s16x8*)qp;
    qf1 = *(const s16x8*)(qp + 32);
  }

  f32x4 acc[4] = {};
  float mrun[4] = {-1e30f, -1e30f, -1e30f, -1e30f};
  float lsum[4] = {0.f, 0.f, 0.f, 0.f};
  __syncthreads();  // iiall ready

  for (int kt = 0; kt < 16; ++kt) {
    const int k0 = kt * 64;
    // ---- stage K [key][d] and Vt [d][key] tiles, XOR-swizzled ----
    {
      int srow = tid >> 2, sc2 = (tid & 3) * 2, rx = srow & 7;
      const short* ks = kb + (size_t)(k0 + srow) * 64 + sc2 * 8;
      *(s16x8*)&Kl[srow * 64 + ((sc2 ^ rx) << 3)]       = *(const s16x8*)ks;
      *(s16x8*)&Kl[srow * 64 + (((sc2 + 1) ^ rx) << 3)] = *(const s16x8*)(ks + 8);
      const short* vs = vtb + (size_t)srow * 1024 + k0 + sc2 * 8;
      *(s16x8*)&Vl[srow * 64 + ((sc2 ^ rx) << 3)]       = *(const s16x8*)vs;
      *(s16x8*)&Vl[srow * 64 + (((sc2 + 1) ^ rx) << 3)] = *(const s16x8*)(vs + 8);
    }
    // ---- mask bitwords (one per q-row r) ----
    unsigned long long mw[4];
#pragma unroll
    for (int r = 0; r < 4; ++r)
      mw[r] = mb[(size_t)kt * 1024 + q0 + w * 16 + lg * 4 + r];
    __syncthreads();  // Kl/Vl ready (also fences previous iteration's reads)

    const int jbase = 960 - k0;
    const int loC  = iiall[w * 16 + jbase] & ~7;        // c2p window base (this wave's q rows)
    const int loPw = iiall[48 - w * 16 + jbase] & ~7;   // p2c window base (this wave's k rows)
    int loP[4];
#pragma unroll
    for (int cb = 0; cb < 4; ++cb) loP[cb] = iiall[48 - cb * 16 + jbase] & ~7;

    // ---- c2p window: [16 q][96 i] = Q_tile · posk[loC..loC+95]^T ----
    {
      f32x4 cacc[6] = {};
#pragma unroll
      for (int cb = 0; cb < 6; ++cb) {
        int i0 = loC + cb * 16 + lr;
        i0 = i0 > 511 ? 511 : i0;
        const short* bp = pkb + (size_t)i0 * 64 + lg * 8;
        s16x8 b0 = *(const s16x8*)bp;
        s16x8 b1 = *(const s16x8*)(bp + 32);
        cacc[cb] = __builtin_amdgcn_mfma_f32_16x16x32_bf16(qf0, b0, cacc[cb], 0, 0, 0);
        cacc[cb] = __builtin_amdgcn_mfma_f32_16x16x32_bf16(qf1, b1, cacc[cb], 0, 0, 0);
      }
#pragma unroll
      for (int cb = 0; cb < 6; ++cb)
#pragma unroll
        for (int r = 0; r < 4; ++r)
          c2pw[w][lg * 4 + r][cb * 16 + lr] = f2bf(cacc[cb][r]);
    }
    // ---- p2c window: [16 k][96 i] = K_tile · posq[loPw..loPw+95]^T ----
    {
      int krow = w * 16 + lr, rx = krow & 7;
      s16x8 ka0 = *(const s16x8*)&Kl[krow * 64 + ((lg ^ rx) << 3)];
      s16x8 ka1 = *(const s16x8*)&Kl[krow * 64 + (((4 + lg) ^ rx) << 3)];
      f32x4 pacc[6] = {};
#pragma unroll
      for (int cb = 0; cb < 6; ++cb) {
        int i0 = loPw + cb * 16 + lr;
        i0 = i0 > 511 ? 511 : i0;
        const short* bp = pqb + (size_t)i0 * 64 + lg * 8;
        s16x8 b0 = *(const s16x8*)bp;
        s16x8 b1 = *(const s16x8*)(bp + 32);
        pacc[cb] = __builtin_amdgcn_mfma_f32_16x16x32_bf16(ka0, b0, pacc[cb], 0, 0, 0);
        pacc[cb] = __builtin_amdgcn_mfma_f32_16x16x32_bf16(ka1, b1, pacc[cb], 0, 0, 0);
      }
#pragma unroll
      for (int cb = 0; cb < 6; ++cb)
#pragma unroll
        for (int r = 0; r < 4; ++r)
          p2cw[w * 16 + lg * 4 + r][cb * 16 + lr] = f2bf(pacc[cb][r]);
    }
    // ---- S = Q K^T (wave: 16 q-rows x 64 keys) ----
    f32x4 sf[4];
#pragma unroll
    for (int cb = 0; cb < 4; ++cb) {
      int krow = cb * 16 + lr, rx = krow & 7;
      s16x8 kf0 = *(const s16x8*)&Kl[krow * 64 + ((lg ^ rx) << 3)];
      s16x8 kf1 = *(const s16x8*)&Kl[krow * 64 + (((4 + lg) ^ rx) << 3)];
      f32x4 z4 = {};
      z4 = __builtin_amdgcn_mfma_f32_16x16x32_bf16(qf0, kf0, z4, 0, 0, 0);
      z4 = __builtin_amdgcn_mfma_f32_16x16x32_bf16(qf1, kf1, z4, 0, 0, 0);
      sf[cb] = z4;
    }
    __syncthreads();  // p2cw ready (c2pw is own-wave)

    // ---- bias gather + mask + scale; online softmax ----
    float pv[4][4];
    float tmax[4] = {-1e30f, -1e30f, -1e30f, -1e30f};
#pragma unroll
    for (int cb = 0; cb < 4; ++cb) {
      int colt = cb * 16 + lr;
#pragma unroll
      for (int r = 0; r < 4; ++r) {
        int rowl = lg * 4 + r;
        int jj = (w * 16 + rowl) - colt + 1023 - k0;
        int i = iiall[jj];
        float bias = bf2f(c2pw[w][rowl][i - loC]) + bf2f(p2cw[colt][i - loP[cb]]);
        float sv = (sf[cb][r] + bias) * INV_SCALE;
        bool ok = (mw[r] >> colt) & 1ull;
        sv = ok ? sv : -1e30f;
        pv[cb][r] = sv;
        tmax[r] = fmaxf(tmax[r], sv);
      }
    }
#pragma unroll
    for (int off = 1; off < 16; off <<= 1)
#pragma unroll
      for (int r = 0; r < 4; ++r) tmax[r] = fmaxf(tmax[r], __shfl_xor(tmax[r], off));
    float alpha[4];
#pragma unroll
    for (int r = 0; r < 4; ++r) {
      float mn = fmaxf(mrun[r], tmax[r]);
      alpha[r] = __expf(mrun[r] - mn);
      mrun[r] = mn;
    }
    float rsum[4] = {0.f, 0.f, 0.f, 0.f};
#pragma unroll
    for (int cb = 0; cb < 4; ++cb)
#pragma unroll
      for (int r = 0; r < 4; ++r) {
        float p = __expf(pv[cb][r] - mrun[r]);
        pv[cb][r] = p;
        rsum[r] += p;
      }
#pragma unroll
    for (int off = 1; off < 16; off <<= 1)
#pragma unroll
      for (int r = 0; r < 4; ++r) rsum[r] += __shfl_xor(rsum[r], off);
#pragma unroll
    for (int r = 0; r < 4; ++r) lsum[r] = lsum[r] * alpha[r] + rsum[r];
#pragma unroll
    for (int d2 = 0; d2 < 4; ++d2)
#pragma unroll
      for (int r = 0; r < 4; ++r) acc[d2][r] *= alpha[r];

    // ---- P -> LDS (alias c2pw[w][*][0..63]; all own-wave gathers are done) ----
#pragma unroll
    for (int cb = 0; cb < 4; ++cb)
#pragma unroll
      for (int r = 0; r < 4; ++r)
        c2pw[w][lg * 4 + r][cb * 16 + lr] = f2bf(pv[cb][r]);

    // ---- acc += P V ----
    s16x8 pa0 = *(const s16x8*)&c2pw[w][lr][lg * 8];
    s16x8 pa1 = *(const s16x8*)&c2pw[w][lr][32 + lg * 8];
#pragma unroll
    for (int d2 = 0; d2 < 4; ++d2) {
      int drow = d2 * 16 + lr, rx = drow & 7;
      s16x8 vf0 = *(const s16x8*)&Vl[drow * 64 + ((lg ^ rx) << 3)];
      s16x8 vf1 = *(const s16x8*)&Vl[drow * 64 + (((4 + lg) ^ rx) << 3)];
      acc[d2] = __builtin_amdgcn_mfma_f32_16x16x32_bf16(pa0, vf0, acc[d2], 0, 0, 0);
      acc[d2] = __builtin_amdgcn_mfma_f32_16x16x32_bf16(pa1, vf1, acc[d2], 0, 0, 0);
    }
    __syncthreads();  // protect Kl/Vl/c2pw/p2cw before next iteration's staging
  }

  // ---- epilogue: ctx[b][q][h*64+d] bf16 ----
  short* ctx = (short*)(wsb + OFF_CTX);
#pragma unroll
  for (int r = 0; r < 4; ++r) {
    float inv = 1.0f / lsum[r];
    int gq = q0 + w * 16 + lg * 4 + r;
#pragma unroll
    for (int d2 = 0; d2 < 4; ++d2) {
      int gd = h * 64 + d2 * 16 + lr;
      ctx[((size_t)b * 1024 + gq) * 1024 + gd] = f2bf(acc[d2][r] * inv);
    }
  }
}

// ---------------- K7: LayerNorm ----------------
__global__ __launch_bounds__(256) void ln_kernel(const char* __restrict__ wsb,
                                                 const float* __restrict__ gamma,
                                                 const float* __restrict__ beta,
                                                 float* __restrict__ out) {
  int row = blockIdx.x, tid = threadIdx.x;
  const float* x = (const float*)(wsb + OFF_X) + (size_t)row * 1024;
  float4 v = ((const float4*)x)[tid];
  float s = v.x + v.y + v.z + v.w;
  float s2 = v.x * v.x + v.y * v.y + v.z * v.z + v.w * v.w;
#pragma unroll
  for (int off = 1; off < 64; off <<= 1) {
    s += __shfl_xor(s, off);
    s2 += __shfl_xor(s2, off);
  }
  __shared__ float ss[4], ss2[4];
  if ((tid & 63) == 0) { ss[tid >> 6] = s; ss2[tid >> 6] = s2; }
  __syncthreads();
  s = ss[0] + ss[1] + ss[2] + ss[3];
  s2 = ss2[0] + ss2[1] + ss2[2] + ss2[3];
  float mu = s * (1.0f / 1024.0f);
  float var = s2 * (1.0f / 1024.0f) - mu * mu;
  float rstd = rsqrtf(var + 1e-7f);
  float4 g = ((const float4*)gamma)[tid];
  float4 be = ((const float4*)beta)[tid];
  float4 o;
  o.x = (v.x - mu) * rstd * g.x + be.x;
  o.y = (v.y - mu) * rstd * g.y + be.y;
  o.z = (v.z - mu) * rstd * g.z + be.z;
  o.w = (v.w - mu) * rstd * g.w + be.w;
  ((float4*)(out + (size_t)row * 1024))[tid] = o;
}

// ---------------- launch ----------------
extern "C" void kernel_launch(void* const* d_in, const int* in_sizes, int n_in,
                              void* d_out, int out_size, void* d_ws, size_t ws_size,
                              hipStream_t stream) {
  const float* hidden = (const float*)d_in[0];
  const int*   mask   = (const int*)d_in[1];
  const float* rel    = (const float*)d_in[2];
  const float* Wq = (const float*)d_in[3];
  const float* bq = (const float*)d_in[4];
  const float* Wk = (const float*)d_in[5];
  const float* bk = (const float*)d_in[6];
  const float* Wv = (const float*)d_in[7];
  const float* bv = (const float*)d_in[8];
  const float* Wo = (const float*)d_in[9];
  const float* bo = (const float*)d_in[10];
  const float* gamma = (const float*)d_in[11];
  const float* beta  = (const float*)d_in[12];
  char* ws = (char*)d_ws;
  float* out = (float*)d_out;

  build_idx<<<dim3(8), dim3(256), 0, stream>>>(ws);
  build_maskbits<<<dim3(8192), dim3(256), 0, stream>>>(mask, ws);
  convert_x<<<dim3(2560), dim3(256), 0, stream>>>(hidden, rel, ws);
  transpose_w<<<dim3(32, 32, 4), dim3(256), 0, stream>>>(Wq, Wk, Wv, Wo, ws);
  // QKV + pos projections (z=0:Wq, 1:Wk, 2:Wv)
  gemm_all<<<dim3(8, 20, 3), dim3(256), 0, stream>>>(ws, 0, bq, bk, bv, bo, hidden);
  // fused attention (computes c2p/p2c windows in-place)
  attn_kernel<<<dim3(32, 16), dim3(256), 0, stream>>>(ws);
  // output projection + bias + residual -> X fp32
  gemm_all<<<dim3(8, 16, 1), dim3(256), 0, stream>>>(ws, 2, bq, bk, bv, bo, hidden);
  ln_kernel<<<dim3(2048), dim3(256), 0, stream>>>(ws, gamma, beta, out);
}